// Round 1
// baseline (628.249 us; speedup 1.0000x reference)
//
#include <hip/hip_runtime.h>

typedef int v4i __attribute__((ext_vector_type(4)));

static constexpr int K_DIM = 4096;
static constexpr int BM = 128, BN = 128, BK = 128;

// ---------------- per-token dynamic quantization ----------------
// one block (256 thr) per token row of 4096 f32; each thread owns 16 elements
__global__ __launch_bounds__(256) void quant_kernel(const float* __restrict__ x,
                                                    signed char* __restrict__ xq,
                                                    float* __restrict__ xs) {
    const int token = blockIdx.x;
    const float4* row = (const float4*)(x + (size_t)token * K_DIM);
    const int t = threadIdx.x;
    float4 v[4];
    float m = 0.f;
#pragma unroll
    for (int i = 0; i < 4; ++i) {
        v[i] = row[t * 4 + i];
        m = fmaxf(m, fabsf(v[i].x));
        m = fmaxf(m, fabsf(v[i].y));
        m = fmaxf(m, fabsf(v[i].z));
        m = fmaxf(m, fabsf(v[i].w));
    }
#pragma unroll
    for (int d = 32; d > 0; d >>= 1) m = fmaxf(m, __shfl_xor(m, d));
    __shared__ float red[4];
    if ((t & 63) == 0) red[t >> 6] = m;
    __syncthreads();
    const float am = fmaxf(fmaxf(red[0], red[1]), fmaxf(red[2], red[3]));
    const float s = fmaxf(am, 1e-8f) * (1.0f / 127.0f);
    const float inv = 127.0f / fmaxf(am, 1e-8f);

    int pk[4];
#pragma unroll
    for (int i = 0; i < 4; ++i) {
        int q0 = (int)fminf(127.f, fmaxf(-127.f, rintf(v[i].x * inv)));
        int q1 = (int)fminf(127.f, fmaxf(-127.f, rintf(v[i].y * inv)));
        int q2 = (int)fminf(127.f, fmaxf(-127.f, rintf(v[i].z * inv)));
        int q3 = (int)fminf(127.f, fmaxf(-127.f, rintf(v[i].w * inv)));
        pk[i] = (q0 & 255) | ((q1 & 255) << 8) | ((q2 & 255) << 16) | (q3 << 24);
    }
    ((int4*)(xq + (size_t)token * K_DIM))[t] = make_int4(pk[0], pk[1], pk[2], pk[3]);
    if (t == 0) xs[token] = s;
}

// ---------------- weight repack: int32 -> packed int8 ----------------
__global__ __launch_bounds__(256) void repack_kernel(const int* __restrict__ w32,
                                                     int4* __restrict__ w8,
                                                     int n16) {
    const int idx = blockIdx.x * 256 + threadIdx.x;
    if (idx >= n16) return;
    const int4* src = (const int4*)w32 + (size_t)idx * 4;
    int4 a = src[0], b = src[1], c = src[2], d = src[3];
    int p0 = (a.x & 255) | ((a.y & 255) << 8) | ((a.z & 255) << 16) | (a.w << 24);
    int p1 = (b.x & 255) | ((b.y & 255) << 8) | ((b.z & 255) << 16) | (b.w << 24);
    int p2 = (c.x & 255) | ((c.y & 255) << 8) | ((c.z & 255) << 16) | (c.w << 24);
    int p3 = (d.x & 255) | ((d.y & 255) << 8) | ((d.z & 255) << 16) | (d.w << 24);
    w8[idx] = make_int4(p0, p1, p2, p3);
}

// ---------------- int8 MFMA GEMM with fused dequant epilogue ----------------
// C[m][n] = (sum_k xq[m][k]*w8[n][k]) * xs[m] * scale[n] + bias[n]
__global__ __launch_bounds__(256) void gemm_kernel(const signed char* __restrict__ xq,
                                                   const signed char* __restrict__ w8,
                                                   const float* __restrict__ xs,
                                                   const float* __restrict__ scale,
                                                   const float* __restrict__ bias,
                                                   float* __restrict__ out,
                                                   int N) {
    __shared__ __align__(16) signed char sA[BM * BK];
    __shared__ __align__(16) signed char sB[BN * BK];

    const int tid = threadIdx.x;
    const int lane = tid & 63;
    const int wid = tid >> 6;
    const int wm = wid >> 1, wn = wid & 1;     // 2x2 wave grid, 64x64 per wave
    const int m0 = blockIdx.y * BM;
    const int n0 = blockIdx.x * BN;

    v4i acc[4][4];
    const v4i vzero = {0, 0, 0, 0};
#pragma unroll
    for (int i = 0; i < 4; ++i)
#pragma unroll
        for (int j = 0; j < 4; ++j) acc[i][j] = vzero;

    // staging geometry: each wave-issue covers 1024B = 8 rows of 128B, lane*16
    const int srow = lane >> 3;                      // row within the 8-row chunk
    const int scol = 16 * ((lane & 7) ^ srow);       // inverse-swizzled source col

    const signed char* gA = xq + (size_t)m0 * K_DIM;
    const signed char* gB = w8 + (size_t)n0 * K_DIM;

    auto stage = [&](int k0) {
#pragma unroll
        for (int i = 0; i < 4; ++i) {
            const int row = i * 32 + wid * 8 + srow;
            const signed char* src = gA + (size_t)row * K_DIM + k0 + scol;
            __builtin_amdgcn_global_load_lds((__attribute__((address_space(1))) void*)src,
                                             (__attribute__((address_space(3))) void*)&sA[i * 4096 + wid * 1024],
                                             16, 0, 0);
        }
#pragma unroll
        for (int i = 0; i < 4; ++i) {
            const int row = i * 32 + wid * 8 + srow;
            const signed char* src = gB + (size_t)row * K_DIM + k0 + scol;
            __builtin_amdgcn_global_load_lds((__attribute__((address_space(1))) void*)src,
                                             (__attribute__((address_space(3))) void*)&sB[i * 4096 + wid * 1024],
                                             16, 0, 0);
        }
    };

    stage(0);

    const int a_row = wm * 64 + (lane & 15);
    const int b_row = wn * 64 + (lane & 15);
    const int kq = (lane >> 4) * 16;       // k-offset quarter within 64
    const int sw = (lane & 7) << 4;        // read-side swizzle (row&7 == lane&7)

    const int NT = K_DIM / BK;
    for (int kt = 0; kt < NT; ++kt) {
        __syncthreads();   // compiler drains vmcnt(0): staged tile visible
#pragma unroll
        for (int ks = 0; ks < 2; ++ks) {
            v4i af[4], bf[4];
#pragma unroll
            for (int mi = 0; mi < 4; ++mi) {
                const int row = a_row + mi * 16;
                const int col = (ks * 64 + kq) ^ sw;
                af[mi] = *(const v4i*)&sA[row * BK + col];
            }
#pragma unroll
            for (int ni = 0; ni < 4; ++ni) {
                const int row = b_row + ni * 16;
                const int col = (ks * 64 + kq) ^ sw;
                bf[ni] = *(const v4i*)&sB[row * BK + col];
            }
#pragma unroll
            for (int mi = 0; mi < 4; ++mi)
#pragma unroll
                for (int ni = 0; ni < 4; ++ni)
                    acc[mi][ni] = __builtin_amdgcn_mfma_i32_16x16x64_i8(af[mi], bf[ni], acc[mi][ni], 0, 0, 0);
        }
        if (kt + 1 < NT) {
            __syncthreads();   // all waves done reading before overwrite
            stage((kt + 1) * BK);
        }
    }

    // epilogue: D reg r of lane l -> row (l>>4)*4+r, col l&15 (per 16x16 frag)
    const int mrow0 = m0 + wm * 64 + ((lane >> 4) << 2);
    const int ncol0 = n0 + wn * 64 + (lane & 15);
    float xsv[4][4];
#pragma unroll
    for (int mi = 0; mi < 4; ++mi)
#pragma unroll
        for (int r = 0; r < 4; ++r) xsv[mi][r] = xs[mrow0 + mi * 16 + r];

#pragma unroll
    for (int ni = 0; ni < 4; ++ni) {
        const int n = ncol0 + ni * 16;
        const float sc = scale[n];
        const float bs = bias[n];
#pragma unroll
        for (int mi = 0; mi < 4; ++mi) {
#pragma unroll
            for (int r = 0; r < 4; ++r) {
                const int m = mrow0 + mi * 16 + r;
                out[(size_t)m * N + n] = (float)acc[mi][ni][r] * xsv[mi][r] * sc + bs;
            }
        }
    }
}

extern "C" void kernel_launch(void* const* d_in, const int* in_sizes, int n_in,
                              void* d_out, int out_size, void* d_ws, size_t ws_size,
                              hipStream_t stream) {
    const float* x     = (const float*)d_in[0];
    const int*   w32   = (const int*)d_in[1];
    const float* scale = (const float*)d_in[2];
    const float* bias  = (const float*)d_in[3];
    float* out = (float*)d_out;

    const int M = in_sizes[0] / K_DIM;   // 8192
    const int N = in_sizes[2];           // 11008

    char* ws = (char*)d_ws;
    signed char* xq = (signed char*)ws;                                  // M*K bytes
    float* xs = (float*)(ws + (size_t)M * K_DIM);                        // M floats
    signed char* w8 = (signed char*)(ws + (size_t)M * K_DIM + (size_t)M * sizeof(float));  // N*K bytes

    quant_kernel<<<M, 256, 0, stream>>>(x, xq, xs);

    const int n16 = (N * K_DIM) / 16;
    repack_kernel<<<(n16 + 255) / 256, 256, 0, stream>>>(w32, (int4*)w8, n16);

    gemm_kernel<<<dim3(N / BN, M / BM), 256, 0, stream>>>(xq, w8, xs, scale, bias, out, N);
}